// Round 15
// baseline (269.864 us; speedup 1.0000x reference)
//
#include <hip/hip_runtime.h>

#define NUM_RELS 19
#define NPB 256        // nodes per bucket (power of 2)
#define NPB_SHIFT 8
#define MAXB 400       // max buckets (N <= 102400)
#define NBLK 512       // partition chunk-blocks
#define NK (NPB * NUM_RELS)   // 4864 (node,rel) keys per bucket
#define SCAP 6144      // LDS sorted-record capacity per bucket (avg ~4096, 16+ sigma margin)

typedef _Float16 half8 __attribute__((ext_vector_type(8)));
typedef float floatx4 __attribute__((ext_vector_type(4)));

// record pack: dstlocal(8b)<<22 | src(17b)<<5 | etype(5b)

// ---------------- W2/W3 -> f16 B-fragment swizzle + bcnt zero ----------------

__global__ void wswz_kernel(const float* __restrict__ W2, const float* __restrict__ W3,
                            _Float16* __restrict__ W2F, _Float16* __restrict__ W3F,
                            int* __restrict__ bcnt, int B) {
    int idx = blockIdx.x * blockDim.x + threadIdx.x;
    if (idx < B) bcnt[idx] = 0;
    if (idx >= NUM_RELS * 1024 + 1024) return;
    if (idx < NUM_RELS * 1024) {
        int j = idx & 7, lane = (idx >> 3) & 63, nt = (idx >> 9) & 1, r = idx >> 10;
        int k = (lane >> 4) * 8 + j, n = nt * 16 + (lane & 15);
        W2F[idx] = (_Float16)W2[r * 1024 + k * 32 + n];
    } else {
        int li = idx - NUM_RELS * 1024;
        int j = li & 7, lane = (li >> 3) & 63, nt = (li >> 9) & 1;
        int k = (lane >> 4) * 8 + j, n = nt * 16 + (lane & 15);
        W3F[li] = (_Float16)W3[k * 32 + n];
    }
}

// ---------------- pass A: per-block bucket histogram ----------------

__global__ __launch_bounds__(512) void count_kernel(const int* __restrict__ dst,
                                                    int* __restrict__ blkhist,
                                                    int* __restrict__ bcnt,
                                                    int E, int B, int chunk) {
    __shared__ int h[MAXB];
    for (int i = threadIdx.x; i < B; i += 512) h[i] = 0;
    __syncthreads();
    int e0 = blockIdx.x * chunk, e1 = min(E, e0 + chunk);
    for (int e = e0 + (int)threadIdx.x; e < e1; e += 512)
        atomicAdd(&h[dst[e] >> NPB_SHIFT], 1);
    __syncthreads();
    for (int i = threadIdx.x; i < B; i += 512) {
        blkhist[blockIdx.x * B + i] = h[i];
        if (h[i]) atomicAdd(&bcnt[i], h[i]);
    }
}

// ---------------- offsets: pbase + per-bucket scan across chunk-blocks ----------------

__global__ __launch_bounds__(NBLK) void offscan_kernel(const int* __restrict__ blkhist,
                                                       const int* __restrict__ bcnt,
                                                       int* __restrict__ pbase,
                                                       int* __restrict__ offs, int B) {
    __shared__ int lds[NBLK];
    __shared__ int pbs;
    int bucket = blockIdx.x;
    int t = threadIdx.x;

    int c = (t < B) ? ((bcnt[t] + 7) & ~7) : 0;
    lds[t] = c;
    __syncthreads();
    for (int off = 1; off < NBLK; off <<= 1) {
        int x = (t >= off) ? lds[t - off] : 0;
        __syncthreads();
        lds[t] += x;
        __syncthreads();
    }
    if (t == bucket) {
        pbs = lds[t] - c;
        pbase[bucket] = pbs;
    }
    __syncthreads();
    int myp = pbs;

    int v = blkhist[t * B + bucket];
    lds[t] = v;
    __syncthreads();
    for (int off = 1; off < NBLK; off <<= 1) {
        int x = (t >= off) ? lds[t - off] : 0;
        __syncthreads();
        lds[t] += x;
        __syncthreads();
    }
    offs[t * B + bucket] = myp + lds[t] - v;
}

// ---------------- pass B: scatter 4B packed records with deterministic offsets ----------------

__global__ __launch_bounds__(512) void scatter2_kernel(
    const int* __restrict__ src, const int* __restrict__ dst, const int* __restrict__ etype,
    const int* __restrict__ offs, unsigned* __restrict__ recs4, int E, int B, int chunk) {
    __shared__ int cur[MAXB];
    for (int i = threadIdx.x; i < B; i += 512) cur[i] = offs[blockIdx.x * B + i];
    __syncthreads();
    int e0 = blockIdx.x * chunk, e1 = min(E, e0 + chunk);
    for (int e = e0 + (int)threadIdx.x; e < e1; e += 512) {
        int d = dst[e];
        int b = d >> NPB_SHIFT;
        int pos = atomicAdd(&cur[b], 1);
        recs4[pos] = ((unsigned)(d & (NPB - 1)) << 22) | ((unsigned)src[e] << 5) | (unsigned)etype[e];
    }
}

// ---------------- layer 1 per bucket: cnt2 LDS histogram -> h1 (f16, global) ----------------

__global__ __launch_bounds__(256) void l1_kernel(
    const unsigned* __restrict__ recs4, const int* __restrict__ pbase, const int* __restrict__ bcnt,
    const float* __restrict__ W1, const float* __restrict__ b1, _Float16* __restrict__ h1, int N) {
    __shared__ int cnt2[NK];  // 19.4KB
    __shared__ float W1s[NUM_RELS * 32];
    __shared__ float b1s[32];
    int b = blockIdx.x;
    int p0 = pbase[b], n = bcnt[b];
    int t = threadIdx.x;

    for (int i = t; i < NK; i += 256) cnt2[i] = 0;
    for (int i = t; i < NUM_RELS * 32; i += 256) W1s[i] = W1[i];
    if (t < 32) b1s[t] = b1[t];
    __syncthreads();
    for (int i = t; i < n; i += 256) {
        unsigned rec = recs4[p0 + i];
        atomicAdd(&cnt2[(rec >> 22) * NUM_RELS + (rec & 31)], 1);
    }
    __syncthreads();
    int o = t & 31, hw = t >> 5;
    int v0 = b << NPB_SHIFT;
    for (int k = hw; k < NPB; k += 8) {
        int vv = v0 + k;
        if (vv >= N) break;
        float acc = b1s[o];
        const int* cp = &cnt2[k * NUM_RELS];
#pragma unroll
        for (int r = 0; r < NUM_RELS; ++r) acc += (float)cp[r] * W1s[r * 32 + o];
        h1[(size_t)vv * 32 + o] = (_Float16)fmaxf(acc, 0.f);
    }
}

// ---------------- aggregate: LDS sort by (node,rel) -> gather h1 -> agg[r][v] rows ----------------
// The gather target is h1 (6.4MB, L2/L3-resident) instead of round-14's g (121MB, HBM-latency).
// Records sorted entirely in LDS (no global CSR). Per half-wave per node: edge23-proven
// coalesced rec-tile + shfl + 4-deep gather, with rel-boundary flush writing agg rows
// (zero-filling empty (v,r) pairs -> agg is dense for the GEMM).

__global__ __launch_bounds__(512) void agg_kernel(
    const unsigned* __restrict__ recs4, const int* __restrict__ pbase, const int* __restrict__ bcnt,
    const _Float16* __restrict__ h1, _Float16* __restrict__ agg, int N) {
    __shared__ int goff[NK];   // counts -> exclusive offsets (bucket-local)
    __shared__ int cur[NK];    // scatter cursors -> group ends
    __shared__ int srec[SCAP]; // sorted records (src<<5|etype); also scan scratch
    int b = blockIdx.x;
    int p0 = pbase[b];
    int n = min(bcnt[b], SCAP);
    int t = threadIdx.x;

    for (int i = t; i < NK; i += 512) goff[i] = 0;
    __syncthreads();
    for (int i = t; i < n; i += 512) {
        unsigned rec = recs4[p0 + i];
        atomicAdd(&goff[(rec >> 22) * NUM_RELS + (rec & 31)], 1);
    }
    __syncthreads();

    // blocked exclusive scan of goff (10 keys/thread), scratch in srec
    int base = t * 10;
    int cnt[10];
    int s = 0;
#pragma unroll
    for (int q = 0; q < 10; ++q) {
        int i = base + q;
        int v = (i < NK) ? goff[i] : 0;
        cnt[q] = v;
        s += v;
    }
    srec[t] = s;
    __syncthreads();
    for (int off = 1; off < 512; off <<= 1) {
        int x = (t >= off) ? srec[t - off] : 0;
        __syncthreads();
        srec[t] += x;
        __syncthreads();
    }
    int run = srec[t] - s;  // exclusive
    __syncthreads();        // all reads of scratch done before srec reused
#pragma unroll
    for (int q = 0; q < 10; ++q) {
        int i = base + q;
        if (i < NK) {
            goff[i] = run;
            cur[i] = run;
            run += cnt[q];
        }
    }
    __syncthreads();

    // scatter records into LDS, sorted by (node, rel)
    for (int i = t; i < n; i += 512) {
        unsigned rec = recs4[p0 + i];
        int key = (rec >> 22) * NUM_RELS + (rec & 31);
        int pos = atomicAdd(&cur[key], 1);
        srec[pos] = (int)(rec & 0x3FFFFFu);  // src<<5 | etype
    }
    __syncthreads();

    // per half-wave per node: gather + rel-boundary flush
    int o = t & 31, hw = t >> 5;  // 16 half-waves
    int v0n = b << NPB_SHIFT;
    const int N32 = N * 32;
    for (int ln = hw; ln < NPB; ln += 16) {
        int v = v0n + ln;
        if (v >= N) continue;
        int k0 = ln * NUM_RELS;
        int ns = goff[k0];
        int ne = cur[k0 + NUM_RELS - 1];
        int vbase = v * 32 + o;

        int cur_r = 0;
        float acc = 0.f;
        for (int bb = ns; bb < ne; bb += 32) {
            int idx = bb + o;
            int m_l = (idx < ne) ? srec[idx] : 0;  // coalesced LDS tile
            int cnt_ = min(32, ne - bb);
            int j = 0;
            for (; j + 4 <= cnt_; j += 4) {
                int m[4];
                float x[4];
#pragma unroll
                for (int k = 0; k < 4; ++k) {
                    m[k] = __shfl(m_l, j + k, 32);
                    x[k] = (float)h1[(m[k] >> 5) * 32 + o];  // L2-resident gather
                }
#pragma unroll
                for (int k = 0; k < 4; ++k) {
                    int r = m[k] & 31;
                    if (r != cur_r) {
                        agg[(size_t)cur_r * N32 + vbase] = (_Float16)acc;
                        for (int rr = cur_r + 1; rr < r; ++rr)
                            agg[(size_t)rr * N32 + vbase] = (_Float16)0.f;
                        cur_r = r;
                        acc = 0.f;
                    }
                    acc += x[k];
                }
            }
            for (; j < cnt_; ++j) {
                int m = __shfl(m_l, j, 32);
                float x = (float)h1[(m >> 5) * 32 + o];
                int r = m & 31;
                if (r != cur_r) {
                    agg[(size_t)cur_r * N32 + vbase] = (_Float16)acc;
                    for (int rr = cur_r + 1; rr < r; ++rr)
                        agg[(size_t)rr * N32 + vbase] = (_Float16)0.f;
                    cur_r = r;
                    acc = 0.f;
                }
                acc += x;
            }
        }
        // final flush: write acc at cur_r, zero the rest
        agg[(size_t)cur_r * N32 + vbase] = (_Float16)acc;
        for (int rr = cur_r + 1; rr < NUM_RELS; ++rr)
            agg[(size_t)rr * N32 + vbase] = (_Float16)0.f;
    }
}

// ---------------- GEMM: out = relu(sum_r agg[r] @ W2[r] + b2) @ W3 + b3 ----------------
// One wave per 16-node tile, 4 waves/block. 19 MFMAs accumulate across r in AGPRs;
// epilogue transposes h2 through a 1KB LDS tile into A-layout for the W3 MFMA.

__global__ __launch_bounds__(256) void gemm_kernel(
    const _Float16* __restrict__ agg, const _Float16* __restrict__ W2F,
    const _Float16* __restrict__ W3F, const float* __restrict__ b2,
    const float* __restrict__ b3, float* __restrict__ out, int N) {
    __shared__ _Float16 h2t[4][16 * 32];
    int lane = threadIdx.x & 63, wv = threadIdx.x >> 6;
    int ntiles = N / 16;  // N % 16 == 0 for this problem; guard below anyway
    int tile = blockIdx.x * 4 + wv;
    bool valid = tile < ntiles;
    int tilec = valid ? tile : (ntiles - 1);  // clamp loads into valid memory
    int v0 = tilec * 16;
    int col = lane & 15, quad = lane >> 4;
    const int N32 = N * 32;

    floatx4 acc0 = {0.f, 0.f, 0.f, 0.f}, acc1 = {0.f, 0.f, 0.f, 0.f};
    for (int r = 0; r < NUM_RELS; ++r) {
        half8 a = *(const half8*)(agg + (size_t)r * N32 + (v0 + col) * 32 + quad * 8);
        acc0 = __builtin_amdgcn_mfma_f32_16x16x32_f16(a, *(const half8*)(W2F + ((r * 2 + 0) * 64 + lane) * 8), acc0, 0, 0, 0);
        acc1 = __builtin_amdgcn_mfma_f32_16x16x32_f16(a, *(const half8*)(W2F + ((r * 2 + 1) * 64 + lane) * 8), acc1, 0, 0, 0);
    }
    float b2a = b2[col], b2b = b2[16 + col];
#pragma unroll
    for (int reg = 0; reg < 4; ++reg) {
        int row = quad * 4 + reg;
        h2t[wv][row * 32 + col] = (_Float16)fmaxf(acc0[reg] + b2a, 0.f);
        h2t[wv][row * 32 + 16 + col] = (_Float16)fmaxf(acc1[reg] + b2b, 0.f);
    }
    __syncthreads();

    half8 a2 = *(const half8*)(&h2t[wv][col * 32 + quad * 8]);
    float b3a = b3[col], b3b = b3[16 + col];
    floatx4 o0 = {b3a, b3a, b3a, b3a}, o1 = {b3b, b3b, b3b, b3b};
    o0 = __builtin_amdgcn_mfma_f32_16x16x32_f16(a2, *(const half8*)(W3F + (0 * 64 + lane) * 8), o0, 0, 0, 0);
    o1 = __builtin_amdgcn_mfma_f32_16x16x32_f16(a2, *(const half8*)(W3F + (1 * 64 + lane) * 8), o1, 0, 0, 0);
    if (valid) {
#pragma unroll
        for (int reg = 0; reg < 4; ++reg) {
            int row = quad * 4 + reg;
            out[(size_t)(v0 + row) * 32 + col] = o0[reg];
            out[(size_t)(v0 + row) * 32 + 16 + col] = o1[reg];
        }
    }
}

// ---------------- Host launcher ----------------

extern "C" void kernel_launch(void* const* d_in, const int* in_sizes, int n_in,
                              void* d_out, int out_size, void* d_ws, size_t ws_size,
                              hipStream_t stream) {
    const int* src   = (const int*)d_in[0];
    const int* dst   = (const int*)d_in[1];
    const int* etype = (const int*)d_in[2];
    const float* W1  = (const float*)d_in[4];
    const float* b1  = (const float*)d_in[5];
    const float* W2  = (const float*)d_in[6];
    const float* b2  = (const float*)d_in[7];
    const float* W3  = (const float*)d_in[8];
    const float* b3  = (const float*)d_in[9];
    float* out = (float*)d_out;

    int E = in_sizes[0];
    int N = out_size / 32;
    int B = (N + NPB - 1) >> NPB_SHIFT;  // 391 for N=100000

    char* ws = (char*)d_ws;
    size_t off = 0;
    auto alloc = [&](size_t bytes) {
        void* p = ws + off;
        off = (off + bytes + 255) & ~(size_t)255;
        return p;
    };
    int* bcnt       = (int*)alloc((size_t)MAXB * 4);
    int* pbase      = (int*)alloc((size_t)MAXB * 4);
    int* blkhist    = (int*)alloc((size_t)NBLK * MAXB * 4);
    int* offs       = (int*)alloc((size_t)NBLK * MAXB * 4);
    unsigned* recs4 = (unsigned*)alloc(((size_t)E + 8 * MAXB + 64) * 4);
    _Float16* h1    = (_Float16*)alloc((size_t)N * 32 * 2);
    _Float16* agg   = (_Float16*)alloc((size_t)NUM_RELS * N * 32 * 2);
    _Float16* W2F   = (_Float16*)alloc((size_t)NUM_RELS * 1024 * 2);
    _Float16* W3F   = (_Float16*)alloc((size_t)1024 * 2);

    wswz_kernel<<<(NUM_RELS * 1024 + 1024 + 255) / 256, 256, 0, stream>>>(W2, W3, W2F, W3F, bcnt, B);

    int chunk = (E + NBLK - 1) / NBLK;
    count_kernel<<<NBLK, 512, 0, stream>>>(dst, blkhist, bcnt, E, B, chunk);
    offscan_kernel<<<B, NBLK, 0, stream>>>(blkhist, bcnt, pbase, offs, B);
    scatter2_kernel<<<NBLK, 512, 0, stream>>>(src, dst, etype, offs, recs4, E, B, chunk);

    l1_kernel<<<B, 256, 0, stream>>>(recs4, pbase, bcnt, W1, b1, h1, N);
    agg_kernel<<<B, 512, 0, stream>>>(recs4, pbase, bcnt, h1, agg, N);

    int ntiles = N / 16;
    gemm_kernel<<<(ntiles + 3) / 4, 256, 0, stream>>>(agg, W2F, W3F, b2, b3, out, N);
}

// Round 16
// 239.171 us; speedup vs baseline: 1.1283x; 1.1283x over previous
//
#include <hip/hip_runtime.h>

#define NUM_RELS 19
#define NPB 256        // nodes per bucket (power of 2); N assumed % 16 == 0
#define NPB_SHIFT 8
#define MAXB 400       // max buckets (N <= 102400)
#define NBLK 512       // partition chunk-blocks (2 blocks/CU)

typedef _Float16 half8 __attribute__((ext_vector_type(8)));
typedef float floatx4 __attribute__((ext_vector_type(4)));

// record pack: dstlocal(8b)<<22 | src(17b)<<5 | etype(5b)   (rec < 2^30)
// recs2 = rec & 0x3FFFFF  ->  src<<5 | etype (edge23's proven format)

// ---------------- W2 -> f16 B-fragment swizzle + bcnt zero ----------------

__global__ void w2swz_kernel(const float* __restrict__ W2, _Float16* __restrict__ W2F,
                             int* __restrict__ bcnt, int B) {
    int idx = blockIdx.x * blockDim.x + threadIdx.x;
    if (idx < B) bcnt[idx] = 0;
    if (idx >= NUM_RELS * 2 * 64 * 8) return;
    int j = idx & 7, lane = (idx >> 3) & 63, nt = (idx >> 9) & 1, r = idx >> 10;
    int k = (lane >> 4) * 8 + j, n = nt * 16 + (lane & 15);
    W2F[idx] = (_Float16)W2[r * 1024 + k * 32 + n];
}

// ---------------- pass A: per-block bucket histogram (also produces bcnt totals) ----------------

__global__ __launch_bounds__(512) void count_kernel(const int* __restrict__ dst,
                                                    int* __restrict__ blkhist,
                                                    int* __restrict__ bcnt,
                                                    int E, int B, int chunk) {
    __shared__ int h[MAXB];
    for (int i = threadIdx.x; i < B; i += 512) h[i] = 0;
    __syncthreads();
    int e0 = blockIdx.x * chunk, e1 = min(E, e0 + chunk);
    for (int e = e0 + (int)threadIdx.x; e < e1; e += 512)
        atomicAdd(&h[dst[e] >> NPB_SHIFT], 1);
    __syncthreads();
    for (int i = threadIdx.x; i < B; i += 512) {
        blkhist[blockIdx.x * B + i] = h[i];
        if (h[i]) atomicAdd(&bcnt[i], h[i]);
    }
}

// ---------------- offsets: pbase + per-bucket scan across chunk-blocks ----------------

__global__ __launch_bounds__(NBLK) void offscan_kernel(const int* __restrict__ blkhist,
                                                       const int* __restrict__ bcnt,
                                                       int* __restrict__ pbase,
                                                       int* __restrict__ offs, int B) {
    __shared__ int lds[NBLK];
    __shared__ int pbs;
    int bucket = blockIdx.x;
    int t = threadIdx.x;

    int c = (t < B) ? ((bcnt[t] + 7) & ~7) : 0;
    lds[t] = c;
    __syncthreads();
    for (int off = 1; off < NBLK; off <<= 1) {
        int x = (t >= off) ? lds[t - off] : 0;
        __syncthreads();
        lds[t] += x;
        __syncthreads();
    }
    if (t == bucket) {
        pbs = lds[t] - c;
        pbase[bucket] = pbs;
    }
    __syncthreads();
    int myp = pbs;

    int v = blkhist[t * B + bucket];
    lds[t] = v;
    __syncthreads();
    for (int off = 1; off < NBLK; off <<= 1) {
        int x = (t >= off) ? lds[t - off] : 0;
        __syncthreads();
        lds[t] += x;
        __syncthreads();
    }
    offs[t * B + bucket] = myp + lds[t] - v;
}

// ---------------- pass B: scatter 4B packed records + (src,rel) reference flags ----------------
// flag2[r*N+u]=1 marks that g row (u,r) will be gathered by edge23. Duplicate plain byte
// stores are harmless; 1.6M random 1B stores land in a 1.9MB region -> L2-absorbed.

__global__ __launch_bounds__(512) void scatter2_kernel(
    const int* __restrict__ src, const int* __restrict__ dst, const int* __restrict__ etype,
    const int* __restrict__ offs, unsigned* __restrict__ recs4,
    unsigned char* __restrict__ flag2, int E, int B, int chunk, int N) {
    __shared__ int cur[MAXB];
    for (int i = threadIdx.x; i < B; i += 512) cur[i] = offs[blockIdx.x * B + i];
    __syncthreads();
    int e0 = blockIdx.x * chunk, e1 = min(E, e0 + chunk);
    for (int e = e0 + (int)threadIdx.x; e < e1; e += 512) {
        int d = dst[e];
        int s = src[e];
        int r = etype[e];
        int b = d >> NPB_SHIFT;
        int pos = atomicAdd(&cur[b], 1);
        recs4[pos] = ((unsigned)(d & (NPB - 1)) << 22) | ((unsigned)s << 5) | (unsigned)r;
        flag2[(size_t)r * N + s] = 1;
    }
}

// ---------------- bucket sort + layer1 + MFMA transform, fully fused ----------------
// Round-14 verified structure. New: g stores predicated on flag2 — unreferenced (u,r) rows
// (~43% at E/(N*R)=0.84) are never read by edge23, so skipping their writes is safe and cuts
// ~52MB of the 121MB g write.

__global__ __launch_bounds__(512) void bsort_l1t_kernel(
    const unsigned* __restrict__ recs4, const int* __restrict__ pbase, const int* __restrict__ bcnt,
    int* __restrict__ recs2, int* __restrict__ row_start, int* __restrict__ rend,
    const float* __restrict__ W1, const float* __restrict__ b1,
    const _Float16* __restrict__ W2F, const unsigned char* __restrict__ flag2,
    _Float16* __restrict__ g, int N) {
    __shared__ int hist[NPB];
    __shared__ int offsl[NPB];
    __shared__ int cur[NPB];
    __shared__ int cnt2[NPB * NUM_RELS];     // 19.4KB
    __shared__ float W1s[NUM_RELS * 32];
    __shared__ float b1s[32];
    __shared__ _Float16 h1t[NPB * 32];       // 16KB bucket h1 tile
    int b = blockIdx.x;
    int p0 = pbase[b], n = bcnt[b];
    int t = threadIdx.x;

    if (t < NPB) hist[t] = 0;
    for (int i = t; i < NPB * NUM_RELS; i += 512) cnt2[i] = 0;
    for (int i = t; i < NUM_RELS * 32; i += 512) W1s[i] = W1[i];
    if (t < 32) b1s[t] = b1[t];
    __syncthreads();

    for (int i = t; i < n; i += 512) {
        unsigned rec = recs4[p0 + i];
        int ln = rec >> 22;
        atomicAdd(&hist[ln], 1);
        atomicAdd(&cnt2[ln * NUM_RELS + (rec & 31)], 1);
    }
    __syncthreads();
    int c = 0;
    if (t < NPB) {
        c = hist[t];
        offsl[t] = c;
    }
    __syncthreads();
    for (int off = 1; off < NPB; off <<= 1) {
        int x = 0;
        if (t < NPB && t >= off) x = offsl[t - off];
        __syncthreads();
        if (t < NPB) offsl[t] += x;
        __syncthreads();
    }
    if (t < NPB) {
        int start = p0 + offsl[t] - c;  // exclusive
        cur[t] = start;
        int v = (b << NPB_SHIFT) + t;
        if (v < N) {
            row_start[v] = start;
            rend[v] = start + c;
        }
    }
    __syncthreads();
    for (int i = t; i < n; i += 512) {
        unsigned rec = recs4[p0 + i];  // L2-hot (just read above)
        int p = atomicAdd(&cur[rec >> 22], 1);
        recs2[p] = (int)(rec & 0x3FFFFFu);  // src<<5 | etype
    }

    // layer 1 into the LDS tile (f16)
    int o = t & 31, hw = t >> 5;  // 16 half-waves
    int v0n = b << NPB_SHIFT;
    for (int k = hw; k < NPB; k += 16) {
        int vv = v0n + k;
        float acc = b1s[o];
        const int* cp = &cnt2[k * NUM_RELS];
#pragma unroll
        for (int r = 0; r < NUM_RELS; ++r) acc += (float)cp[r] * W1s[r * 32 + o];
        h1t[k * 32 + o] = (vv < N) ? (_Float16)fmaxf(acc, 0.f) : (_Float16)0.f;
    }
    __syncthreads();

    // MFMA transform for this bucket's 16 node-tiles (N % 16 == 0: per-tile guard only)
    int lane = t & 63;
    int wv = t >> 6;  // 8 waves
    floatx4 zero = {0.f, 0.f, 0.f, 0.f};
    int row = (lane >> 4) * 4;
    int col = lane & 15;
    for (int tile = wv; tile < NPB / 16; tile += 8) {
        int v0g = v0n + tile * 16;
        if (v0g >= N) continue;
        half8 a = *(const half8*)(h1t + (tile * 16 + (lane & 15)) * 32 + (lane >> 4) * 8);
        for (int r = 0; r < NUM_RELS; ++r) {
            _Float16* gbase = g + ((size_t)r * N + v0g) * 32;
            // 4 flags for this quad's 4 nodes (rows row..row+3); broadcast across the quad.
            // Offset r*N + v0g + row is 4-aligned when N%4==0 (true here).
            unsigned fw;
            __builtin_memcpy(&fw, flag2 + (size_t)r * N + v0g + row, 4);
#pragma unroll
            for (int nt = 0; nt < 2; ++nt) {
                half8 bfrag = *(const half8*)(W2F + ((r * 2 + nt) * 64 + lane) * 8);
                floatx4 d = __builtin_amdgcn_mfma_f32_16x16x32_f16(a, bfrag, zero, 0, 0, 0);
#pragma unroll
                for (int reg = 0; reg < 4; ++reg) {
                    if ((fw >> (8 * reg)) & 0xFFu)
                        gbase[(row + reg) * 32 + nt * 16 + col] = (_Float16)d[reg];
                }
            }
        }
    }
}

// ---------------- Edge phase + layer 3 fused (frozen at its gather roofline) ----------------

__global__ __launch_bounds__(512) void edge23_kernel(
    const _Float16* __restrict__ g, const int* __restrict__ row_start,
    const int* __restrict__ rend, const int* __restrict__ recs2,
    const float* __restrict__ b2, const float* __restrict__ W3, const float* __restrict__ b3,
    float* __restrict__ out, int N) {
    __shared__ float W3s[1024];
    __shared__ float b2s[32], b3s[32];
    for (int i = threadIdx.x; i < 1024; i += 512) W3s[i] = W3[i];
    if (threadIdx.x < 32) {
        b2s[threadIdx.x] = b2[threadIdx.x];
        b3s[threadIdx.x] = b3[threadIdx.x];
    }
    __syncthreads();

    int o = threadIdx.x & 31;
    int hw = blockIdx.x * 16 + (threadIdx.x >> 5);  // node id
    if (hw >= N) return;
    int start = row_start[hw], end = rend[hw];
    const int sN32 = N * 32;

    float acc = b2s[o];
    for (int base = start; base < end; base += 32) {
        int idx = base + o;
        int m_l = (idx < end) ? recs2[idx] : 0;
        int cnt = min(32, end - base);
        int j = 0;
        for (; j + 4 <= cnt; j += 4) {
            float x[4];
#pragma unroll
            for (int k = 0; k < 4; ++k) {
                int m = __shfl(m_l, j + k, 32);
                x[k] = (float)g[(m & 31) * sN32 + (m >> 5) * 32 + o];
            }
            acc += ((x[0] + x[1]) + (x[2] + x[3]));
        }
        for (; j < cnt; ++j) {
            int m = __shfl(m_l, j, 32);
            acc += (float)g[(m & 31) * sN32 + (m >> 5) * 32 + o];
        }
    }
    float h2v = fmaxf(acc, 0.f);

    float acc3 = b3s[o];
#pragma unroll
    for (int i = 0; i < 32; ++i) {
        float hi = __shfl(h2v, i, 32);
        acc3 = fmaf(hi, W3s[i * 32 + o], acc3);
    }
    out[(size_t)hw * 32 + o] = acc3;
}

// ---------------- Host launcher ----------------

extern "C" void kernel_launch(void* const* d_in, const int* in_sizes, int n_in,
                              void* d_out, int out_size, void* d_ws, size_t ws_size,
                              hipStream_t stream) {
    const int* src   = (const int*)d_in[0];
    const int* dst   = (const int*)d_in[1];
    const int* etype = (const int*)d_in[2];
    const float* W1  = (const float*)d_in[4];
    const float* b1  = (const float*)d_in[5];
    const float* W2  = (const float*)d_in[6];
    const float* b2  = (const float*)d_in[7];
    const float* W3  = (const float*)d_in[8];
    const float* b3  = (const float*)d_in[9];
    float* out = (float*)d_out;

    int E = in_sizes[0];
    int N = out_size / 32;
    int B = (N + NPB - 1) >> NPB_SHIFT;  // 391 for N=100000

    char* ws = (char*)d_ws;
    size_t off = 0;
    auto alloc = [&](size_t bytes) {
        void* p = ws + off;
        off = (off + bytes + 255) & ~(size_t)255;
        return p;
    };
    int* bcnt           = (int*)alloc((size_t)MAXB * 4);
    int* pbase          = (int*)alloc((size_t)MAXB * 4);
    int* blkhist        = (int*)alloc((size_t)NBLK * MAXB * 4);
    int* offs           = (int*)alloc((size_t)NBLK * MAXB * 4);
    int* row_start      = (int*)alloc((size_t)N * 4);
    int* rend           = (int*)alloc((size_t)N * 4);
    unsigned* recs4     = (unsigned*)alloc(((size_t)E + 8 * MAXB + 64) * 4);
    int* recs2          = (int*)alloc(((size_t)E + 8 * MAXB + 64) * 4);
    unsigned char* flag2 = (unsigned char*)alloc((size_t)NUM_RELS * N + 64);
    _Float16* g         = (_Float16*)alloc((size_t)NUM_RELS * N * 32 * 2);
    _Float16* W2F       = (_Float16*)alloc((size_t)NUM_RELS * 2 * 64 * 8 * 2);

    w2swz_kernel<<<(NUM_RELS * 2 * 64 * 8 + 255) / 256, 256, 0, stream>>>(W2, W2F, bcnt, B);

    int chunk = (E + NBLK - 1) / NBLK;
    count_kernel<<<NBLK, 512, 0, stream>>>(dst, blkhist, bcnt, E, B, chunk);
    offscan_kernel<<<B, NBLK, 0, stream>>>(blkhist, bcnt, pbase, offs, B);
    hipMemsetAsync(flag2, 0, (size_t)NUM_RELS * N, stream);
    scatter2_kernel<<<NBLK, 512, 0, stream>>>(src, dst, etype, offs, recs4, flag2, E, B, chunk, N);

    bsort_l1t_kernel<<<B, 512, 0, stream>>>(recs4, pbase, bcnt, recs2, row_start, rend,
                                            W1, b1, W2F, flag2, g, N);

    edge23_kernel<<<(N + 15) / 16, 512, 0, stream>>>(g, row_start, rend, recs2, b2, W3, b3, out, N);
}